// Round 3
// baseline (118.236 us; speedup 1.0000x reference)
//
#include <hip/hip_runtime.h>
#include <hip/hip_bf16.h>
#include <float.h>

// Problem constants (B, N, M from the reference)
#define B_      8
#define N_      8192
#define M_      8192
#define THREADS 256
#define P       8                    // a-points per thread (ILP)
#define SPLIT   32                   // M-loop split factor (parallelism)
#define CHUNK   (M_ / SPLIT)         // 256 b-points per block
#define APB     (THREADS * P)        // 2048 a-points per block
#define ATILES  (N_ / APB)           // 4 a-tiles per (batch, dir)
#define NBLOCKS (2 * SPLIT * ATILES * B_)  // 2048

// Pack xyz [n,3] -> float4 (x, y, z, x^2+y^2+z^2)
__global__ void pack_kernel(const float* __restrict__ xyz,
                            float4* __restrict__ out, int n) {
    int i = blockIdx.x * blockDim.x + threadIdx.x;
    if (i < n) {
        float x = xyz[3 * i + 0];
        float y = xyz[3 * i + 1];
        float z = xyz[3 * i + 2];
        out[i] = make_float4(x, y, z, fmaf(x, x, fmaf(y, y, z * z)));
    }
}

// Init output to FLT_MAX (atomicMin target); re-run every call (graph-safe)
__global__ void init_kernel(float* __restrict__ out, int n) {
    int i = blockIdx.x * blockDim.x + threadIdx.x;
    if (i < n) out[i] = FLT_MAX;
}

// Main kernel, packed-ws variant. Both directions fused in one grid.
// __launch_bounds__(256, 4): 4 waves/EU min -> VGPR cap 128. The round-2
// build (no 2nd arg) allocated only 32 VGPRs and shuffled the per-thread
// arrays through AGPRs (v_accvgpr_read/write), ~2.3x the VALU instr count.
__global__ __launch_bounds__(THREADS, 4) void chamfer_ws(
    const float4* __restrict__ pk1,   // packed xyz1 [B*N]
    const float4* __restrict__ pk2,   // packed xyz2 [B*M]
    float* __restrict__ out)          // [B*N] dist1 then [B*M] dist2
{
    int bid = blockIdx.x;
    int dir   = bid & 1;                 bid >>= 1;
    int chunk = bid & (SPLIT - 1);       bid /= SPLIT;    // pow2 -> shift
    int atile = bid & (ATILES - 1);      bid /= ATILES;
    int batch = bid;                                      // 0..B_-1

    const float4* A  = dir ? pk2 : pk1;
    const float4* Bp = dir ? pk1 : pk2;
    float* o = out + (dir ? (B_ * N_) : 0);

    const int a0 = batch * N_ + atile * APB + threadIdx.x;

    float ax2[P], ay2[P], az2[P], aw[P], m[P];
#pragma unroll
    for (int p = 0; p < P; ++p) {
        float4 a = A[a0 + p * THREADS];   // coalesced: lane-consecutive float4
        ax2[p] = -2.0f * a.x;
        ay2[p] = -2.0f * a.y;
        az2[p] = -2.0f * a.z;
        aw[p]  = a.w;
        m[p]   = FLT_MAX;
    }

    // b-points: wave-uniform address -> broadcast via L1; chunk is 4 KB
    const float4* bp = Bp + batch * M_ + chunk * CHUNK;
#pragma unroll 2
    for (int j = 0; j < CHUNK; j += 2) {
        float4 b0 = bp[j];
        float4 b1 = bp[j + 1];
#pragma unroll
        for (int p = 0; p < P; ++p) {
            float t0 = fmaf(ax2[p], b0.x, b0.w);
            t0 = fmaf(ay2[p], b0.y, t0);
            t0 = fmaf(az2[p], b0.z, t0);
            float t1 = fmaf(ax2[p], b1.x, b1.w);
            t1 = fmaf(ay2[p], b1.y, t1);
            t1 = fmaf(az2[p], b1.z, t1);
            m[p] = fminf(m[p], fminf(t0, t1));   // fuses to v_min3_f32
        }
    }

#pragma unroll
    for (int p = 0; p < P; ++p) {
        float d = fmaxf(aw[p] + m[p], 0.0f);     // clamp: keeps uint-min valid
        atomicMin((unsigned int*)(o + a0 + p * THREADS), __float_as_uint(d));
    }
}

// Fallback variant if ws is too small: read raw [.,3] coords, norms inline.
__global__ __launch_bounds__(THREADS, 4) void chamfer_raw(
    const float* __restrict__ xyz1,
    const float* __restrict__ xyz2,
    float* __restrict__ out)
{
    int bid = blockIdx.x;
    int dir   = bid & 1;                 bid >>= 1;
    int chunk = bid & (SPLIT - 1);       bid /= SPLIT;
    int atile = bid & (ATILES - 1);      bid /= ATILES;
    int batch = bid;

    const float* A  = dir ? xyz2 : xyz1;
    const float* Bp = dir ? xyz1 : xyz2;
    float* o = out + (dir ? (B_ * N_) : 0);

    const int a0 = batch * N_ + atile * APB + threadIdx.x;

    float ax2[P], ay2[P], az2[P], aw[P], m[P];
#pragma unroll
    for (int p = 0; p < P; ++p) {
        int idx = a0 + p * THREADS;
        float x = A[3 * idx + 0];
        float y = A[3 * idx + 1];
        float z = A[3 * idx + 2];
        ax2[p] = -2.0f * x;
        ay2[p] = -2.0f * y;
        az2[p] = -2.0f * z;
        aw[p]  = fmaf(x, x, fmaf(y, y, z * z));
        m[p]   = FLT_MAX;
    }

    const float* bp = Bp + 3 * (batch * M_ + chunk * CHUNK);
#pragma unroll 2
    for (int j = 0; j < CHUNK; j += 2) {
        float b0x = bp[3 * j + 0], b0y = bp[3 * j + 1], b0z = bp[3 * j + 2];
        float b1x = bp[3 * j + 3], b1y = bp[3 * j + 4], b1z = bp[3 * j + 5];
        float b0w = fmaf(b0x, b0x, fmaf(b0y, b0y, b0z * b0z));
        float b1w = fmaf(b1x, b1x, fmaf(b1y, b1y, b1z * b1z));
#pragma unroll
        for (int p = 0; p < P; ++p) {
            float t0 = fmaf(ax2[p], b0x, b0w);
            t0 = fmaf(ay2[p], b0y, t0);
            t0 = fmaf(az2[p], b0z, t0);
            float t1 = fmaf(ax2[p], b1x, b1w);
            t1 = fmaf(ay2[p], b1y, t1);
            t1 = fmaf(az2[p], b1z, t1);
            m[p] = fminf(m[p], fminf(t0, t1));
        }
    }

#pragma unroll
    for (int p = 0; p < P; ++p) {
        float d = fmaxf(aw[p] + m[p], 0.0f);
        atomicMin((unsigned int*)(o + a0 + p * THREADS), __float_as_uint(d));
    }
}

extern "C" void kernel_launch(void* const* d_in, const int* in_sizes, int n_in,
                              void* d_out, int out_size, void* d_ws, size_t ws_size,
                              hipStream_t stream) {
    const float* xyz1 = (const float*)d_in[0];
    const float* xyz2 = (const float*)d_in[1];
    float* out = (float*)d_out;

    const int n_out = B_ * N_ + B_ * M_;   // 131072
    init_kernel<<<(n_out + 255) / 256, 256, 0, stream>>>(out, n_out);

    const size_t need = (size_t)(B_ * (N_ + M_)) * sizeof(float4);  // 2 MiB
    if (ws_size >= need) {
        float4* pk1 = (float4*)d_ws;        // [B*N]
        float4* pk2 = pk1 + (size_t)B_ * N_; // [B*M]
        pack_kernel<<<(B_ * N_ + 255) / 256, 256, 0, stream>>>(xyz1, pk1, B_ * N_);
        pack_kernel<<<(B_ * M_ + 255) / 256, 256, 0, stream>>>(xyz2, pk2, B_ * M_);
        chamfer_ws<<<NBLOCKS, THREADS, 0, stream>>>(pk1, pk2, out);
    } else {
        chamfer_raw<<<NBLOCKS, THREADS, 0, stream>>>(xyz1, xyz2, out);
    }
}

// Round 4
// 98.074 us; speedup vs baseline: 1.2056x; 1.2056x over previous
//
#include <hip/hip_runtime.h>
#include <hip/hip_bf16.h>
#include <float.h>

// Problem constants (B, N, M from the reference)
#define B_      8
#define N_      8192
#define M_      8192
#define THREADS 256
#define P       2                    // a-points per thread (keep VGPRs < 32!)
#define SPLIT   8                    // M-loop split factor
#define CHUNK   (M_ / SPLIT)         // 1024 b-points per block
#define APB     (THREADS * P)        // 512 a-points per block
#define ATILES  (N_ / APB)           // 16 a-tiles per (batch, dir)
#define NBLOCKS (2 * SPLIT * ATILES * B_)  // 2048

typedef float v2f __attribute__((ext_vector_type(2)));

// Pair-SoA pack: for each pair of points (2i, 2i+1) store 8 floats:
// {x0,x1, y0,y1, z0,z1, w0,w1}  where w = x^2+y^2+z^2.
// This layout feeds v_pk_fma_f32 directly (each component is a reg pair).
__global__ void pairpack_kernel(const float* __restrict__ xyz,
                                float* __restrict__ out, int n) {
    int i = blockIdx.x * blockDim.x + threadIdx.x;
    if (i < n) {
        float x = xyz[3 * i + 0];
        float y = xyz[3 * i + 1];
        float z = xyz[3 * i + 2];
        float w = fmaf(x, x, fmaf(y, y, z * z));
        float* g = out + (size_t)(i >> 1) * 8;
        int k = i & 1;
        g[0 + k] = x;
        g[2 + k] = y;
        g[4 + k] = z;
        g[6 + k] = w;
    }
}

// Init output to FLT_MAX (atomicMin target); re-run every call (graph-safe)
__global__ void init_kernel(float* __restrict__ out, int n) {
    int i = blockIdx.x * blockDim.x + threadIdx.x;
    if (i < n) out[i] = FLT_MAX;
}

// Main kernel. a-side read from raw xyz (tiny prologue); b-side from
// pair-SoA ws via wave-uniform loads (scalarize to s_load). Hot loop:
// 3 x v_pk_fma_f32 + 1 x v_min3_f32 per (2 b-points x 1 a-point).
__global__ __launch_bounds__(THREADS, 4) void chamfer_pk(
    const float* __restrict__ xyz1,
    const float* __restrict__ xyz2,
    const v2f* __restrict__ pk1,      // pair-SoA of xyz1 [B*N/2 groups x 4]
    const v2f* __restrict__ pk2,      // pair-SoA of xyz2
    float* __restrict__ out)          // [B*N] dist1 then [B*M] dist2
{
    int bid = blockIdx.x;
    int dir   = bid & 1;                 bid >>= 1;
    int chunk = bid & (SPLIT - 1);       bid /= SPLIT;
    int atile = bid & (ATILES - 1);      bid /= ATILES;
    int batch = bid;                                      // 0..B_-1

    const float* A  = dir ? xyz2 : xyz1;
    const v2f*   Bp = (dir ? pk1 : pk2)
                    + ((size_t)batch * (M_ / 2) + (size_t)chunk * (CHUNK / 2)) * 4;
    float* o = out + (dir ? (B_ * N_) : 0);

    const int a0 = batch * N_ + atile * APB + threadIdx.x;

    v2f axx[P], ayy[P], azz[P];
    float aw[P], m[P];
#pragma unroll
    for (int p = 0; p < P; ++p) {
        int idx = a0 + p * THREADS;
        float x = A[3 * idx + 0];
        float y = A[3 * idx + 1];
        float z = A[3 * idx + 2];
        float nx = -2.0f * x, ny = -2.0f * y, nz = -2.0f * z;
        axx[p] = (v2f){nx, nx};
        ayy[p] = (v2f){ny, ny};
        azz[p] = (v2f){nz, nz};
        aw[p]  = fmaf(x, x, fmaf(y, y, z * z));
        m[p]   = FLT_MAX;
    }

    // CHUNK/2 = 512 groups of 2 b-points each
#pragma unroll 4
    for (int g = 0; g < CHUNK / 2; ++g) {
        v2f bx = Bp[4 * g + 0];
        v2f by = Bp[4 * g + 1];
        v2f bz = Bp[4 * g + 2];
        v2f bw = Bp[4 * g + 3];
#pragma unroll
        for (int p = 0; p < P; ++p) {
            v2f t = __builtin_elementwise_fma(axx[p], bx,
                      __builtin_elementwise_fma(ayy[p], by,
                        __builtin_elementwise_fma(azz[p], bz, bw)));
            // m = min(m, t.lo, t.hi); inputs finite -> NaN semantics moot.
            asm("v_min3_f32 %0, %0, %1, %2"
                : "+v"(m[p])
                : "v"(t.x), "v"(t.y));
        }
    }

#pragma unroll
    for (int p = 0; p < P; ++p) {
        float d = fmaxf(aw[p] + m[p], 0.0f);     // clamp keeps uint-min valid
        atomicMin((unsigned int*)(o + a0 + p * THREADS), __float_as_uint(d));
    }
}

// Fallback if ws too small: raw reads, scalar math (known-good from R2).
#define FP      8
#define FAPB    (THREADS * FP)
#define FATILES (N_ / FAPB)
#define FNBLOCKS (2 * SPLIT * FATILES * B_)
__global__ __launch_bounds__(THREADS) void chamfer_raw(
    const float* __restrict__ xyz1,
    const float* __restrict__ xyz2,
    float* __restrict__ out)
{
    int bid = blockIdx.x;
    int dir   = bid & 1;                 bid >>= 1;
    int chunk = bid & (SPLIT - 1);       bid /= SPLIT;
    int atile = bid & (FATILES - 1);     bid /= FATILES;
    int batch = bid;

    const float* A  = dir ? xyz2 : xyz1;
    const float* Bp = dir ? xyz1 : xyz2;
    float* o = out + (dir ? (B_ * N_) : 0);

    const int a0 = batch * N_ + atile * FAPB + threadIdx.x;

    float ax2[FP], ay2[FP], az2[FP], aw[FP], m[FP];
#pragma unroll
    for (int p = 0; p < FP; ++p) {
        int idx = a0 + p * THREADS;
        float x = A[3 * idx + 0];
        float y = A[3 * idx + 1];
        float z = A[3 * idx + 2];
        ax2[p] = -2.0f * x;
        ay2[p] = -2.0f * y;
        az2[p] = -2.0f * z;
        aw[p]  = fmaf(x, x, fmaf(y, y, z * z));
        m[p]   = FLT_MAX;
    }

    const float* bp = Bp + 3 * (batch * M_ + chunk * CHUNK);
#pragma unroll 2
    for (int j = 0; j < CHUNK; j += 2) {
        float b0x = bp[3 * j + 0], b0y = bp[3 * j + 1], b0z = bp[3 * j + 2];
        float b1x = bp[3 * j + 3], b1y = bp[3 * j + 4], b1z = bp[3 * j + 5];
        float b0w = fmaf(b0x, b0x, fmaf(b0y, b0y, b0z * b0z));
        float b1w = fmaf(b1x, b1x, fmaf(b1y, b1y, b1z * b1z));
#pragma unroll
        for (int p = 0; p < FP; ++p) {
            float t0 = fmaf(ax2[p], b0x, b0w);
            t0 = fmaf(ay2[p], b0y, t0);
            t0 = fmaf(az2[p], b0z, t0);
            float t1 = fmaf(ax2[p], b1x, b1w);
            t1 = fmaf(ay2[p], b1y, t1);
            t1 = fmaf(az2[p], b1z, t1);
            m[p] = fminf(m[p], fminf(t0, t1));
        }
    }

#pragma unroll
    for (int p = 0; p < FP; ++p) {
        float d = fmaxf(aw[p] + m[p], 0.0f);
        atomicMin((unsigned int*)(o + a0 + p * THREADS), __float_as_uint(d));
    }
}

extern "C" void kernel_launch(void* const* d_in, const int* in_sizes, int n_in,
                              void* d_out, int out_size, void* d_ws, size_t ws_size,
                              hipStream_t stream) {
    const float* xyz1 = (const float*)d_in[0];
    const float* xyz2 = (const float*)d_in[1];
    float* out = (float*)d_out;

    const int n_out = B_ * N_ + B_ * M_;   // 131072
    init_kernel<<<(n_out + 255) / 256, 256, 0, stream>>>(out, n_out);

    // pair-SoA for both inputs: B*(N/2 + M/2) groups * 32B = 2 MiB
    const size_t need = (size_t)B_ * (N_ / 2 + M_ / 2) * 8 * sizeof(float);
    if (ws_size >= need) {
        float* pk1 = (float*)d_ws;                       // [B*N/2*8]
        float* pk2 = pk1 + (size_t)B_ * (N_ / 2) * 8;    // [B*M/2*8]
        pairpack_kernel<<<(B_ * N_ + 255) / 256, 256, 0, stream>>>(xyz1, pk1, B_ * N_);
        pairpack_kernel<<<(B_ * M_ + 255) / 256, 256, 0, stream>>>(xyz2, pk2, B_ * M_);
        chamfer_pk<<<NBLOCKS, THREADS, 0, stream>>>(xyz1, xyz2,
                                                    (const v2f*)pk1, (const v2f*)pk2, out);
    } else {
        chamfer_raw<<<FNBLOCKS, THREADS, 0, stream>>>(xyz1, xyz2, out);
    }
}